// Round 1
// 132.753 us; speedup vs baseline: 1.1485x; 1.1485x over previous
//
#include <hip/hip_runtime.h>

#define D 32

// ---------------------------------------------------------------------------
// Kernel 1: Y[r][:] = X[r][:] @ W  for r < n;  Y[n][:] = 0  (zero-gather row)
// One row per wave. X row via scalar (uniform) loads; lane j holds W[:,j].
// ---------------------------------------------------------------------------
__global__ __launch_bounds__(256, 8)
void xw_kernel(const float* __restrict__ X, const float* __restrict__ W,
               float* __restrict__ Y, int n) {
    const int lane = threadIdx.x & 63;
    const int j    = lane & 31;
    const int wid  = blockIdx.x * (blockDim.x >> 6) + (threadIdx.x >> 6);
    const int nw   = gridDim.x * (blockDim.x >> 6);

    // lane j holds column j of W: w[d] = W[d][j]  (coalesced 128B loads)
    float w[D];
    #pragma unroll
    for (int d = 0; d < D; ++d) w[d] = W[d * D + j];

    for (int r = wid; r <= n; r += nw) {
        float o0 = 0.f, o1 = 0.f;
        if (r < n) {
            // wave-uniform row address -> scalar loads (s_load) of the X row
            const float* xr =
                X + (size_t)(unsigned)__builtin_amdgcn_readfirstlane(r) * D;
            #pragma unroll
            for (int d = 0; d < D; d += 2) {
                o0 = fmaf(xr[d],     w[d],     o0);
                o1 = fmaf(xr[d + 1], w[d + 1], o1);
            }
        }
        if (lane < 32) Y[(size_t)r * D + j] = o0 + o1;
    }
}

// ---------------------------------------------------------------------------
// Kernel 2: out[r][:] = sum_{e in row r} Y[ci[e]][:]
// One row per wave; 8 edges x 8 float4-slots per gather instruction;
// invalid slots gather the zero row Y[n] (no masking VALU at all).
// ---------------------------------------------------------------------------
template <int K>
__device__ __forceinline__ void gather_acc(const float* __restrict__ Y,
                                           int myci, int base, int g, int s,
                                           float4& acc) {
    float4 x[K];
    #pragma unroll
    for (int it = 0; it < K; ++it) {
        int c = __shfl(myci, (base + it) * 8 + g, 64);   // zrow for invalid
        x[it] = ((const float4*)(Y + (size_t)(unsigned)c * D))[s];
    }
    #pragma unroll
    for (int it = 0; it < K; ++it) {
        acc.x += x[it].x; acc.y += x[it].y;
        acc.z += x[it].z; acc.w += x[it].w;
    }
}

__global__ __launch_bounds__(256, 8)
void agg_kernel(const float* __restrict__ Y, const int* __restrict__ rp,
                const int* __restrict__ ci, float* __restrict__ out, int n) {
    const int tid  = threadIdx.x;
    const int wave = tid >> 6;
    const int lane = tid & 63;
    int row = blockIdx.x * 4 + wave;
    if (row >= n) return;
    row = __builtin_amdgcn_readfirstlane(row);   // scalar rp loads

    const int start = rp[row];
    const int deg   = rp[row + 1] - start;

    const int g  = lane >> 3;   // edge sub-group 0..7
    const int s  = lane & 7;    // float4 slot 0..7
    const int zr = n;           // zero row index

    float4 acc = make_float4(0.f, 0.f, 0.f, 0.f);

    for (int cb = 0; cb < deg; cb += 64) {
        const int rem  = deg - cb;
        const int nv   = rem < 64 ? rem : 64;
        const int myci = (lane < nv) ? ci[start + cb + lane] : zr;

        switch ((nv + 7) >> 3) {            // wave-uniform branch ladder
            case 1: gather_acc<1>(Y, myci, 0, g, s, acc); break;
            case 2: gather_acc<2>(Y, myci, 0, g, s, acc); break;
            case 3: gather_acc<3>(Y, myci, 0, g, s, acc); break;
            case 4: gather_acc<4>(Y, myci, 0, g, s, acc); break;
            case 5: gather_acc<4>(Y, myci, 0, g, s, acc);
                    gather_acc<1>(Y, myci, 4, g, s, acc); break;
            case 6: gather_acc<4>(Y, myci, 0, g, s, acc);
                    gather_acc<2>(Y, myci, 4, g, s, acc); break;
            case 7: gather_acc<4>(Y, myci, 0, g, s, acc);
                    gather_acc<3>(Y, myci, 4, g, s, acc); break;
            default: gather_acc<4>(Y, myci, 0, g, s, acc);
                     gather_acc<4>(Y, myci, 4, g, s, acc); break;
        }
    }

    // Reduce across the 8 edge groups (xor over g bits: 8, 16, 32)
    #pragma unroll
    for (int off = 8; off < 64; off <<= 1) {
        acc.x += __shfl_xor(acc.x, off, 64);
        acc.y += __shfl_xor(acc.y, off, 64);
        acc.z += __shfl_xor(acc.z, off, 64);
        acc.w += __shfl_xor(acc.w, off, 64);
    }
    // lanes 0..7 hold the final row: slot s -> out[row][4s..4s+3]
    if (lane < 8) ((float4*)(out + (size_t)row * D))[s] = acc;
}

// ---------------------------------------------------------------------------
// Legacy fused kernel (fallback if workspace is too small for Y)
// ---------------------------------------------------------------------------
__global__ __launch_bounds__(256, 4)
void gin_fused(const float* __restrict__ X,
               const float* __restrict__ W,
               const int* __restrict__ rp,
               const int* __restrict__ ci,
               float* __restrict__ out,
               int n) {
    __shared__ float Wl[D * D];

    int tid = threadIdx.x;
    {
        const float4* Wv = (const float4*)W;
        float4* Wlv = (float4*)Wl;
        Wlv[tid] = Wv[tid];
    }
    __syncthreads();

    int wave = tid >> 6;
    int lane = tid & 63;
    int row = blockIdx.x * 4 + wave;
    if (row >= n) return;

    int start = rp[row];
    int deg   = rp[row + 1] - start;

    int g = lane >> 3;
    int s = lane & 7;

    float4 acc = make_float4(0.f, 0.f, 0.f, 0.f);

    for (int cb = 0; cb < deg; cb += 64) {
        int rem = deg - cb;
        int nv  = rem < 64 ? rem : 64;
        int myci = (lane < nv) ? ci[start + cb + lane] : 0;
        {
            float4 x[4]; float m[4];
            #pragma unroll
            for (int it = 0; it < 4; ++it) {
                int l = it * 8 + g;
                int c = __shfl(myci, l, 64);
                m[it] = (l < rem) ? 1.f : 0.f;
                x[it] = ((const float4*)(X + (size_t)c * D))[s];
            }
            #pragma unroll
            for (int it = 0; it < 4; ++it) {
                acc.x = fmaf(m[it], x[it].x, acc.x);
                acc.y = fmaf(m[it], x[it].y, acc.y);
                acc.z = fmaf(m[it], x[it].z, acc.z);
                acc.w = fmaf(m[it], x[it].w, acc.w);
            }
        }
        if (rem > 32) {
            float4 x[4]; float m[4];
            #pragma unroll
            for (int it = 0; it < 4; ++it) {
                int l = (it + 4) * 8 + g;
                int c = __shfl(myci, l, 64);
                m[it] = (l < rem) ? 1.f : 0.f;
                x[it] = ((const float4*)(X + (size_t)c * D))[s];
            }
            #pragma unroll
            for (int it = 0; it < 4; ++it) {
                acc.x = fmaf(m[it], x[it].x, acc.x);
                acc.y = fmaf(m[it], x[it].y, acc.y);
                acc.z = fmaf(m[it], x[it].z, acc.z);
                acc.w = fmaf(m[it], x[it].w, acc.w);
            }
        }
    }

    #pragma unroll
    for (int off = 8; off < 64; off <<= 1) {
        acc.x += __shfl_xor(acc.x, off, 64);
        acc.y += __shfl_xor(acc.y, off, 64);
        acc.z += __shfl_xor(acc.z, off, 64);
        acc.w += __shfl_xor(acc.w, off, 64);
    }

    int j = lane & 31;
    float o = 0.f;
    #pragma unroll
    for (int sg = 0; sg < 8; ++sg) {
        float ax = __shfl(acc.x, sg, 64);
        float ay = __shfl(acc.y, sg, 64);
        float az = __shfl(acc.z, sg, 64);
        float aw = __shfl(acc.w, sg, 64);
        int d = 4 * sg;
        o = fmaf(ax, Wl[(d    ) * D + j], o);
        o = fmaf(ay, Wl[(d + 1) * D + j], o);
        o = fmaf(az, Wl[(d + 2) * D + j], o);
        o = fmaf(aw, Wl[(d + 3) * D + j], o);
    }
    if (lane < 32) out[(size_t)row * D + j] = o;
}

extern "C" void kernel_launch(void* const* d_in, const int* in_sizes, int n_in,
                              void* d_out, int out_size, void* d_ws, size_t ws_size,
                              hipStream_t stream) {
    const float* X  = (const float*)d_in[0];
    const float* W  = (const float*)d_in[1];
    const int*   rp = (const int*)d_in[2];
    const int*   ci = (const int*)d_in[3];
    float* out = (float*)d_out;

    int n = in_sizes[2] - 1;                       // N nodes
    size_t ybytes = (size_t)(n + 1) * D * sizeof(float);

    if (ws_size >= ybytes) {
        float* Y = (float*)d_ws;
        hipLaunchKernelGGL(xw_kernel, dim3(1024), dim3(256), 0, stream,
                           X, W, Y, n);
        hipLaunchKernelGGL(agg_kernel, dim3((n + 3) / 4), dim3(256), 0, stream,
                           Y, rp, ci, out, n);
    } else {
        hipLaunchKernelGGL(gin_fused, dim3((n + 3) / 4), dim3(256), 0, stream,
                           X, W, rp, ci, out, n);
    }
}